// Round 1
// 124.203 us; speedup vs baseline: 1.0379x; 1.0379x over previous
//
#include <hip/hip_runtime.h>
#include <math.h>

#define NROWS 65536
#define BN_EPS 1e-5f
#define MBLK   512    // main-kernel grid: 128 rows per block, 2 rows/thread
#define TSTR   1024   // ws_blkT stride: colsums use idx=blk (<512), BN use blk*2+set (<1024)

// ---- workspace layout (floats) ----
// OFF_PARTIAL : per-row partial                                        [65536]
// OFF_H       : h[row*8+j]                                             [524288]
// OFF_REC     : packed per-feature record rec[f][84]                   [5376]
//               0..15 U=W1+W2 | 16..31 B1 | 32..47 B2 | 48..55 A1
//               56..63 A2 | 64..71 A3 | 72 QU 73 QB1 74 QB2 75 2QUB1
//               76 2QUB2 77 2QB1B2 | 78 w1 79 b1 80 b2 | 81..83 pad
// OFF_BLKT    : per-block stats transposed blkT[v*1024+idx], v<80      [81920]
//               v 0..63 Xc colsum (idx=blk, 512 valid)
//               v 64..71 sum h_j, 72..79 sum h_j^2 (idx=blk*2+set, 1024 valid)
// OFF_T       : reduced totals                                         [96]
#define OFF_PARTIAL 0
#define OFF_H       65536
#define OFF_REC     589824
#define OFF_BLKT    595200
#define OFF_T       677120

// 64 blocks x 64 threads: block f builds rec[f][*].  (proven R4-R11)
__global__ __launch_bounds__(64) void precompute_kernel(
    const float* __restrict__ W1, const float* __restrict__ B1,
    const float* __restrict__ W2, const float* __restrict__ B2,
    const float* __restrict__ lin1_w, const float* __restrict__ w1,
    const float* __restrict__ b1, const float* __restrict__ b2,
    float* __restrict__ rec)
{
    int f = blockIdx.x, t = threadIdx.x;
    __shared__ float u[16], x[16], y[16];
    if (t < 16) {
        float uu = W1[f * 16 + t] + W2[f * 16 + t];
        float xx = B1[f * 16 + t];
        float yy = B2[f * 16 + t];
        u[t] = uu; x[t] = xx; y[t] = yy;
        rec[f * 84 + t]      = uu;
        rec[f * 84 + 16 + t] = xx;
        rec[f * 84 + 32 + t] = yy;
    }
    __syncthreads();
    if (t < 24) {
        int j = t & 7, which = t >> 3;
        const float* src = (which == 0) ? u : (which == 1) ? x : y;
        const float* lw = lin1_w + j * 1024 + f * 16;
        float acc = 0.f;
#pragma unroll
        for (int e = 0; e < 16; e++) acc = fmaf(src[e], lw[e], acc);
        rec[f * 84 + 48 + which * 8 + j] = acc;
    } else if (t < 30) {
        int q = t - 24;
        const float* s1 = (q == 0 || q == 3 || q == 4) ? u : (q == 1 || q == 5) ? x : y;
        const float* s2 = (q == 0) ? u : (q == 1 || q == 3) ? x : y;
        float acc = 0.f;
#pragma unroll
        for (int e = 0; e < 16; e++) acc = fmaf(s1[e], s2[e], acc);
        rec[f * 84 + 72 + q] = (q < 3 ? 1.f : 2.f) * acc;
    } else if (t == 30) {
        rec[f * 84 + 78] = w1[f];
        rec[f * 84 + 79] = b1[f];
        rec[f * 84 + 80] = b2[f];
        rec[f * 84 + 81] = 0.f;
        rec[f * 84 + 82] = 0.f;
        rec[f * 84 + 83] = 0.f;
    }
}

// 512 blocks x 256 threads, 2 ROWS PER THREAD (rows row0 and row0+64).
// Theory (this round): hot loop is LDS-issue-bound on wave-uniform broadcast
// ds_read_b128 (16 useful B per instr, full issue cost on the CU-shared LDS
// pipe). Doubling rows/wave halves per-CU LDS instrs (5376 -> 2688) at equal
// VALU efficiency; lost occupancy (4 -> 2 waves/SIMD) is compensated by two
// independent per-row dependency chains.
// waves_per_eu(2,4) -> 256-VGPR budget (grid only supplies 2 waves/SIMD).
// unroll 1 prevents R5's full-unroll ds_read hoisting -> VGPR explosion.
// Colsum butterfly AFTER the hot loop (R10 lesson: shfl shares lgkmcnt).
__global__ __launch_bounds__(256)
__attribute__((amdgpu_waves_per_eu(2, 4)))
void main_kernel(
    const float* __restrict__ Xa, const float* __restrict__ Xc,
    const float* __restrict__ rec, const float* __restrict__ lin1_b,
    float* __restrict__ ws_partial, float* __restrict__ ws_h,
    float* __restrict__ ws_blkT)
{
    // [0,5376) = rec staging during phase B; then cmb[2][4][64][29] (aliased,
    // barrier-separated -- R4-proven pattern)
    __shared__ __align__(16) float smem[14848];

    int tid  = threadIdx.x;
    int lane = tid & 63;
    int wv   = tid >> 6;
    int wu   = __builtin_amdgcn_readfirstlane(wv);
    int blk  = blockIdx.x;
    int f0   = wu * 16;
    int row0 = blk * 128 + lane;
    int row1 = row0 + 64;

    // stage rec -> LDS (coalesced float4, ~21.5 KB)
    {
        const float4* src = (const float4*)rec;
        float4* dst = (float4*)smem;
        for (int i = tid; i < 1344; i += 256) dst[i] = src[i];
    }

    // per-lane a/c for both rows (R7-proven register layout)
    const float4* pa0 = (const float4*)(Xa + (size_t)row0 * 64 + f0);
    const float4* pc0 = (const float4*)(Xc + (size_t)row0 * 64 + f0);
    const float4* pa1 = (const float4*)(Xa + (size_t)row1 * 64 + f0);
    const float4* pc1 = (const float4*)(Xc + (size_t)row1 * 64 + f0);
    float a_[16], c_[16], a2_[16], c2_[16];
#pragma unroll
    for (int k = 0; k < 4; k++) {
        float4 av = pa0[k], cv = pc0[k];
        a_[k * 4] = av.x; a_[k * 4 + 1] = av.y; a_[k * 4 + 2] = av.z; a_[k * 4 + 3] = av.w;
        c_[k * 4] = cv.x; c_[k * 4 + 1] = cv.y; c_[k * 4 + 2] = cv.z; c_[k * 4 + 3] = cv.w;
        float4 av2 = pa1[k], cv2 = pc1[k];
        a2_[k * 4] = av2.x; a2_[k * 4 + 1] = av2.y; a2_[k * 4 + 2] = av2.z; a2_[k * 4 + 3] = av2.w;
        c2_[k * 4] = cv2.x; c2_[k * 4 + 1] = cv2.y; c2_[k * 4 + 2] = cv2.z; c2_[k * 4 + 3] = cv2.w;
    }
    __syncthreads();   // rec staged

    float s[16], s2[16], hh[8], hh2[8];
#pragma unroll
    for (int e = 0; e < 16; e++) { s[e] = 0.f; s2[e] = 0.f; }
#pragma unroll
    for (int j = 0; j < 8; j++) { hh[j] = 0.f; hh2[j] = 0.f; }
    float p1_0 = 0.f, p2a_0 = 0.f, q_0 = 0.f;
    float p1_1 = 0.f, p2a_1 = 0.f, q_1 = 0.f;

    const float* recw = smem + f0 * 84;
#pragma unroll 1
    for (int i = 0; i < 16; i++) {
        const float* r = recw + i * 84;   // wave-uniform -> LDS broadcast
        float a0 = a_[i],  c0 = c_[i];
        float a1 = a2_[i], c1 = c2_[i];
        float pp0 = a0 * c0, pp1 = a1 * c1;

        float rw1 = r[78], rb1 = r[79], rb2 = r[80];
        p1_0  = fmaf(fmaf(rw1, a0, rb1), c0, p1_0);
        p1_1  = fmaf(fmaf(rw1, a1, rb1), c1, p1_1);
        p2a_0 = fmaf(a0, rb2, p2a_0);
        p2a_1 = fmaf(a1, rb2, p2a_1);

        float q0 = r[72], q1 = r[73], q2 = r[74], q3 = r[75], q4 = r[76], q5 = r[77];
        q_0 = fmaf(pp0 * pp0, q0, q_0);
        q_0 = fmaf(c0 * c0,   q1, q_0);
        q_0 = fmaf(a0 * a0,   q2, q_0);
        q_0 = fmaf(pp0 * c0,  q3, q_0);
        q_0 = fmaf(pp0 * a0,  q4, q_0);
        q_0 = fmaf(pp0,       q5, q_0);
        q_1 = fmaf(pp1 * pp1, q0, q_1);
        q_1 = fmaf(c1 * c1,   q1, q_1);
        q_1 = fmaf(a1 * a1,   q2, q_1);
        q_1 = fmaf(pp1 * c1,  q3, q_1);
        q_1 = fmaf(pp1 * a1,  q4, q_1);
        q_1 = fmaf(pp1,       q5, q_1);

#pragma unroll
        for (int e = 0; e < 16; e++) {
            float u = r[e], x = r[16 + e], y = r[32 + e];
            s[e]  = fmaf(pp0, u, fmaf(c0, x, fmaf(a0, y, s[e])));
            s2[e] = fmaf(pp1, u, fmaf(c1, x, fmaf(a1, y, s2[e])));
        }
#pragma unroll
        for (int j = 0; j < 8; j++) {
            float w1c = r[48 + j], w2c = r[56 + j], w3c = r[64 + j];
            hh[j]  = fmaf(pp0, w1c, fmaf(c0, w2c, fmaf(a0, w3c, hh[j])));
            hh2[j] = fmaf(pp1, w1c, fmaf(c1, w2c, fmaf(a1, w3c, hh2[j])));
        }
    }

    // Xc column sums over this block's 128 rows (pair-sum, then butterfly)
    {
        float cs[16];
#pragma unroll
        for (int i = 0; i < 16; i++) cs[i] = c_[i] + c2_[i];
#pragma unroll
        for (int off = 1; off < 64; off <<= 1) {
#pragma unroll
            for (int i = 0; i < 16; i++) cs[i] += __shfl_xor(cs[i], off);
        }
        if (lane == 0) {
#pragma unroll
            for (int i = 0; i < 16; i++)
                ws_blkT[(size_t)(f0 + i) * TSTR + blk] = cs[i];
        }
    }

    // cross-wave combine (aliases rec region; barrier retires table reads)
    __syncthreads();
    {
        float* cmb0 = smem + (wv * 64 + lane) * 29;
        float* cmb1 = smem + 7424 + (wv * 64 + lane) * 29;
#pragma unroll
        for (int e = 0; e < 16; e++) { cmb0[e] = s[e]; cmb1[e] = s2[e]; }
#pragma unroll
        for (int j = 0; j < 8; j++) { cmb0[16 + j] = hh[j]; cmb1[16 + j] = hh2[j]; }
        cmb0[24] = p1_0;  cmb1[24] = p1_1;
        cmb0[25] = p2a_0; cmb1[25] = p2a_1;
        cmb0[26] = q_0;   cmb1[26] = q_1;
    }
    __syncthreads();

    if (tid < 128) {
        int set = tid >> 6;        // set 0: rows +0..63 (wave 0), set 1: rows +64..127 (wave 1)
        int l   = tid & 63;
        const float* base = smem + set * 7424;
        float S[16], H[8], P1 = 0.f, P2 = 0.f, Q = 0.f;
#pragma unroll
        for (int e = 0; e < 16; e++) S[e] = 0.f;
#pragma unroll
        for (int j = 0; j < 8; j++) H[j] = 0.f;
#pragma unroll
        for (int w = 0; w < 4; w++) {
            const float* c2 = base + (w * 64 + l) * 29;
#pragma unroll
            for (int e = 0; e < 16; e++) S[e] += c2[e];
#pragma unroll
            for (int j = 0; j < 8; j++) H[j] += c2[16 + j];
            P1 += c2[24];
            P2 += c2[25];
            Q  += c2[26];
        }
#pragma unroll
        for (int j = 0; j < 8; j++) H[j] += lin1_b[j];

        float ss = 0.f;
#pragma unroll
        for (int e = 0; e < 16; e++) ss = fmaf(S[e], S[e], ss);
        int rr = blk * 128 + set * 64 + l;
        ws_partial[rr] = (P1 + P2) * (1.f / 64.f) + (ss - Q) * (0.5f / 16.f);
        *(float4*)(ws_h + (size_t)rr * 8)     = make_float4(H[0], H[1], H[2], H[3]);
        *(float4*)(ws_h + (size_t)rr * 8 + 4) = make_float4(H[4], H[5], H[6], H[7]);

        // BN partials over this set's 64 rows (butterfly stays in-wave: set==wave)
        float bn[16];
#pragma unroll
        for (int j = 0; j < 8; j++) { bn[j] = H[j]; bn[8 + j] = H[j] * H[j]; }
#pragma unroll
        for (int off = 1; off < 64; off <<= 1) {
#pragma unroll
            for (int i = 0; i < 16; i++) bn[i] += __shfl_xor(bn[i], off);
        }
        if (l == 0) {
#pragma unroll
            for (int i = 0; i < 16; i++)
                ws_blkT[(size_t)(64 + i) * TSTR + blk * 2 + set] = bn[i];
        }
    }
}

// 80 waves: one per statistic. v<64 (colsums): 512 partials; v>=64 (BN): 1024.
__global__ __launch_bounds__(256) void reduce_kernel(
    const float* __restrict__ ws_blkT, float* __restrict__ T)
{
    int gtid = blockIdx.x * 256 + threadIdx.x;
    int v = gtid >> 6;
    int lane = gtid & 63;
    const float* p = ws_blkT + (size_t)v * TSTR + lane;
    float acc = 0.f;
    if (v < 64) {
#pragma unroll
        for (int k = 0; k < 8; k++) acc += p[k * 64];
    } else {
#pragma unroll
        for (int k = 0; k < 16; k++) acc += p[k * 64];
    }
#pragma unroll
    for (int off = 32; off; off >>= 1) acc += __shfl_xor(acc, off);
    if (lane == 0) T[v] = acc;
}

// 512 blocks x 256 threads: two threads per row. (R8-proven)
__global__ __launch_bounds__(256) void final_kernel(
    const float* __restrict__ Xa, const float* __restrict__ w2,
    const float* __restrict__ gamma, const float* __restrict__ beta,
    const float* __restrict__ lin2_w, const float* __restrict__ lin2_b,
    const float* __restrict__ T, const float* __restrict__ ws_partial,
    const float* __restrict__ ws_h, float* __restrict__ out)
{
    __shared__ float sg[64], sScale[8], sShift[8], sColw[8];
    __shared__ float sBsum;
    int tid = threadIdx.x;
    if (tid < 64) {
        sg[tid] = w2[tid] * (T[tid] * (1.f / 65536.f));
    } else if (tid < 72) {
        int j = tid - 64;
        float mu  = T[64 + j] * (1.f / 65536.f);
        float var = T[72 + j] * (1.f / 65536.f) - mu * mu;
        float sc = gamma[j] / sqrtf(var + BN_EPS);
        sScale[j] = sc;
        sShift[j] = beta[j] - mu * sc;
    } else if (tid < 80) {
        int j = tid - 72;
        sColw[j] = lin2_w[j] + lin2_w[8 + j] + lin2_w[16 + j] + lin2_w[24 + j];
    } else if (tid == 80) {
        sBsum = lin2_b[0] + lin2_b[1] + lin2_b[2] + lin2_b[3];
    }
    __syncthreads();

    int row  = (blockIdx.x * 256 + tid) >> 1;
    int half = tid & 1;
    int fo   = half * 32;

    const float4* xa4 = (const float4*)(Xa + (size_t)row * 64 + fo);
    float p2b = 0.f;
#pragma unroll
    for (int k = 0; k < 8; k++) {
        float4 vv = xa4[k];
        int b = fo + k * 4;
        p2b += vv.x * sg[b] + vv.y * sg[b + 1] + vv.z * sg[b + 2] + vv.w * sg[b + 3];
    }

    float4 hq = *(const float4*)(ws_h + (size_t)row * 8 + half * 4);
    float hv[4] = {hq.x, hq.y, hq.z, hq.w};
    float dmp = 0.f;
#pragma unroll
    for (int jj = 0; jj < 4; jj++) {
        int j = half * 4 + jj;
        float hn = tanhf(hv[jj] * sScale[j] + sShift[j]);
        dmp = fmaf(hn, sColw[j], dmp);
    }

    float val = p2b * (1.f / 64.f) + dmp * 0.25f;
    val += __shfl_xor(val, 1);
    if (!half)
        out[row] = val + ws_partial[row] + sBsum * 0.25f;
}

extern "C" void kernel_launch(void* const* d_in, const int* in_sizes, int n_in,
                              void* d_out, int out_size, void* d_ws, size_t ws_size,
                              hipStream_t stream) {
    const float* Xa        = (const float*)d_in[0];
    const float* Xc        = (const float*)d_in[1];
    const float* w1        = (const float*)d_in[2];
    const float* b1        = (const float*)d_in[3];
    const float* w2        = (const float*)d_in[4];
    const float* b2        = (const float*)d_in[5];
    const float* W1        = (const float*)d_in[6];
    const float* B1        = (const float*)d_in[7];
    const float* W2        = (const float*)d_in[8];
    const float* B2        = (const float*)d_in[9];
    const float* lin1_w    = (const float*)d_in[10];
    const float* lin1_b    = (const float*)d_in[11];
    const float* bn1_gamma = (const float*)d_in[12];
    const float* bn1_beta  = (const float*)d_in[13];
    const float* lin2_w    = (const float*)d_in[14];
    const float* lin2_b    = (const float*)d_in[15];

    float* ws  = (float*)d_ws;
    float* out = (float*)d_out;

    float* ws_partial = ws + OFF_PARTIAL;
    float* ws_h       = ws + OFF_H;
    float* ws_rec     = ws + OFF_REC;
    float* ws_blkT    = ws + OFF_BLKT;
    float* ws_T       = ws + OFF_T;

    precompute_kernel<<<64, 64, 0, stream>>>(W1, B1, W2, B2, lin1_w,
                                             w1, b1, b2, ws_rec);
    main_kernel<<<MBLK, 256, 0, stream>>>(Xa, Xc, ws_rec, lin1_b,
                                          ws_partial, ws_h, ws_blkT);
    reduce_kernel<<<20, 256, 0, stream>>>(ws_blkT, ws_T);
    final_kernel<<<512, 256, 0, stream>>>(Xa, w2, bn1_gamma, bn1_beta,
                                          lin2_w, lin2_b, ws_T,
                                          ws_partial, ws_h, out);
}